// Round 8
// baseline (349.047 us; speedup 1.0000x reference)
//
#include <hip/hip_runtime.h>
#include <hip/hip_bf16.h>

// GIN: 2 x (CSR gather-sum + MLP(64->64->64) + BatchNorm + ReLU) + mean pool
// N=50000 nodes, E=800000 edges, H=64, G=16 graphs. fp32 in/out.
// R8: place_kernel stores csr with nontemporal hint (R7: 51.5MB WRITE_SIZE for
// a 3.2MB array = 64B write-allocate per random 4B store; nt streams past L2).
// agg gather pipeline deepened 4 -> 8 independent accumulators (more MLP).

constexpr int NN = 50000;
constexpr int NE = 800000;
constexpr int HD = 64;
constexpr int NG = 16;
constexpr float BN_EPS = 1e-5f;
constexpr int SCAN_BLOCKS = (NN + 255) / 256;  // 196

// ---------------------------------------------------------------------------
// CSR build: degree histogram -> exclusive scan -> edge placement.
// ---------------------------------------------------------------------------
__global__ __launch_bounds__(256)
void count_kernel(const int* __restrict__ ei, int* __restrict__ cnt) {
    int e = blockIdx.x * 256 + threadIdx.x;
    if (e >= NE) return;
    atomicAdd(&cnt[ei[NE + e]], 1);
}

__global__ __launch_bounds__(256)
void scan1_kernel(const int* __restrict__ cnt, int* __restrict__ row_ptr,
                  int* __restrict__ partials) {
    int i = blockIdx.x * 256 + threadIdx.x;
    int v = (i < NN) ? cnt[i] : 0;
    __shared__ int s[256];
    s[threadIdx.x] = v;
    __syncthreads();
#pragma unroll
    for (int off = 1; off < 256; off <<= 1) {
        int add = (threadIdx.x >= off) ? s[threadIdx.x - off] : 0;
        __syncthreads();
        s[threadIdx.x] += add;
        __syncthreads();
    }
    if (i < NN) row_ptr[i] = s[threadIdx.x] - v;  // exclusive
    if (threadIdx.x == 255) partials[blockIdx.x] = s[255];
}

__global__ __launch_bounds__(256)
void scan2_kernel(int* __restrict__ partials, int* __restrict__ poffs) {
    int v = (threadIdx.x < SCAN_BLOCKS) ? partials[threadIdx.x] : 0;
    __shared__ int s[256];
    s[threadIdx.x] = v;
    __syncthreads();
#pragma unroll
    for (int off = 1; off < 256; off <<= 1) {
        int add = (threadIdx.x >= off) ? s[threadIdx.x - off] : 0;
        __syncthreads();
        s[threadIdx.x] += add;
        __syncthreads();
    }
    poffs[threadIdx.x] = s[threadIdx.x] - v;  // exclusive
}

__global__ __launch_bounds__(256)
void scan3_kernel(int* __restrict__ row_ptr, const int* __restrict__ poffs,
                  int* __restrict__ cursor) {
    int i = blockIdx.x * 256 + threadIdx.x;
    if (i < NN) {
        int v = row_ptr[i] + poffs[blockIdx.x];
        row_ptr[i] = v;
        cursor[i] = v;
    }
    if (i == 0) row_ptr[NN] = NE;
}

__global__ __launch_bounds__(256)
void place_kernel(const int* __restrict__ ei, int* __restrict__ cursor,
                  int* __restrict__ csr) {
    int e = blockIdx.x * 256 + threadIdx.x;
    if (e >= NE) return;
    int src = ei[e];
    int pos = atomicAdd(&cursor[ei[NE + e]], 1);
    __builtin_nontemporal_store(src, &csr[pos]);  // stream past L2: no 64B
                                                  // write-allocate per 4B store
}

// ---------------------------------------------------------------------------
// fp32 -> bf16 table conversion. Also zeroes cnt[] for the following
// count_kernel (stream order guarantees completion first).
// ---------------------------------------------------------------------------
__global__ __launch_bounds__(256)
void x2bf_kernel(const float* __restrict__ x, __hip_bfloat16* __restrict__ xb,
                 int* __restrict__ cnt) {
    int i4 = blockIdx.x * 256 + threadIdx.x;
    if (i4 < NN) cnt[i4] = 0;
    if (i4 >= NN * HD / 4) return;
    float4 v = *(const float4*)(x + (size_t)i4 * 4);
    union { ushort4 u; __hip_bfloat16 b[4]; } p;
    p.b[0] = __float2bfloat16(v.x);
    p.b[1] = __float2bfloat16(v.y);
    p.b[2] = __float2bfloat16(v.z);
    p.b[3] = __float2bfloat16(v.w);
    *(ushort4*)((unsigned short*)xb + (size_t)i4 * 4) = p.u;
}

// ---------------------------------------------------------------------------
// Aggregation: one wave per dst row. h[r] = x_f32[r] + sum_nb bf16(x)[nb].
// Gather pipeline 8 deep (8 independent outstanding loads per lane). Block 0
// zeroes stats for the following mlp_kernel.
// ---------------------------------------------------------------------------
__global__ __launch_bounds__(256)
void agg_kernel(const float* __restrict__ x, const __hip_bfloat16* __restrict__ xb,
                const int* __restrict__ row_ptr, const int* __restrict__ csr,
                float* __restrict__ h, float* __restrict__ stats) {
    if (blockIdx.x == 0 && threadIdx.x < 128) stats[threadIdx.x] = 0.f;
    int row = blockIdx.x * 4 + (threadIdx.x >> 6);
    int lane = threadIdx.x & 63;
    int s = row_ptr[row], e = row_ptr[row + 1];
    int cnt = e - s;
    int ids = (lane < cnt) ? csr[s + lane] : 0;
    float acc = x[(size_t)row * HD + lane];
    int m = min(cnt, 64);
    int j = 0;
    float a0 = 0.f, a1 = 0.f, a2 = 0.f, a3 = 0.f;
    float a4 = 0.f, a5 = 0.f, a6 = 0.f, a7 = 0.f;
    for (; j + 8 <= m; j += 8) {
        int nb0 = __shfl(ids, j);
        int nb1 = __shfl(ids, j + 1);
        int nb2 = __shfl(ids, j + 2);
        int nb3 = __shfl(ids, j + 3);
        int nb4 = __shfl(ids, j + 4);
        int nb5 = __shfl(ids, j + 5);
        int nb6 = __shfl(ids, j + 6);
        int nb7 = __shfl(ids, j + 7);
        float v0 = __bfloat162float(xb[(size_t)nb0 * HD + lane]);
        float v1 = __bfloat162float(xb[(size_t)nb1 * HD + lane]);
        float v2 = __bfloat162float(xb[(size_t)nb2 * HD + lane]);
        float v3 = __bfloat162float(xb[(size_t)nb3 * HD + lane]);
        float v4 = __bfloat162float(xb[(size_t)nb4 * HD + lane]);
        float v5 = __bfloat162float(xb[(size_t)nb5 * HD + lane]);
        float v6 = __bfloat162float(xb[(size_t)nb6 * HD + lane]);
        float v7 = __bfloat162float(xb[(size_t)nb7 * HD + lane]);
        a0 += v0; a1 += v1; a2 += v2; a3 += v3;
        a4 += v4; a5 += v5; a6 += v6; a7 += v7;
    }
    acc += ((a0 + a1) + (a2 + a3)) + ((a4 + a5) + (a6 + a7));
    for (; j < m; j++) {
        int nb = __shfl(ids, j);
        acc += __bfloat162float(xb[(size_t)nb * HD + lane]);
    }
    for (int jj = s + 64; jj < e; jj++) {  // degree > 64 fallback
        acc += __bfloat162float(xb[(size_t)csr[jj] * HD + lane]);
    }
    h[(size_t)row * HD + lane] = acc;
}

// ---------------------------------------------------------------------------
// Fused MLP + BN-stats epilogue. hout = ReLU(hin @ W1 + b1) @ W2 + b2.
// Block = 128 rows x 256 threads; wave wv owns cols [wv*16,+16); thread does
// rows lane and lane+64. One LDS tile reused input->t->output (barriered).
// Block 0 zeroes psums (only touched by pool kernels, 2 dispatches later).
// ---------------------------------------------------------------------------
__global__ __launch_bounds__(256)
void mlp_kernel(const float* __restrict__ hin, float* __restrict__ hout,
                const float* __restrict__ W1, const float* __restrict__ b1,
                const float* __restrict__ W2, const float* __restrict__ b2,
                float* __restrict__ stats, float* __restrict__ psums) {
    __shared__ float sh[128 * 65];
    __shared__ float sW[64 * 64];
    __shared__ float sb[64];
    __shared__ float red[2][4][64];
    int tid = threadIdx.x;
    int base = blockIdx.x * 128;

    if (blockIdx.x == 0) {
        float4 z = make_float4(0.f, 0.f, 0.f, 0.f);
        *(float4*)(psums + tid * 4) = z;
    }
    for (int i = tid; i < 4096; i += 256) sW[i] = W1[i];
    if (tid < 64) sb[tid] = b1[tid];
#pragma unroll
    for (int i = 0; i < 8; i++) {
        int i4 = tid + 256 * i;          // 0..2047 float4s
        int row = i4 >> 4, col = (i4 & 15) * 4;
        int grow = base + row;
        float4 v = (grow < NN) ? *(const float4*)(hin + (size_t)grow * HD + col)
                               : make_float4(0.f, 0.f, 0.f, 0.f);
        float* d = sh + row * 65 + col;
        d[0] = v.x; d[1] = v.y; d[2] = v.z; d[3] = v.w;
    }
    __syncthreads();

    int wv = tid >> 6;
    int lane = tid & 63;

    float acc0[16], acc1[16];
    // ---- GEMM1 ----
#pragma unroll
    for (int j = 0; j < 16; j++) { acc0[j] = sb[wv * 16 + j]; acc1[j] = acc0[j]; }
    for (int k = 0; k < 64; k++) {
        float a0 = sh[lane * 65 + k];
        float a1 = sh[(64 + lane) * 65 + k];
        const float4* wr = (const float4*)(sW + k * 64 + wv * 16);
#pragma unroll
        for (int q = 0; q < 4; q++) {
            float4 w = wr[q];
            acc0[4 * q + 0] = fmaf(a0, w.x, acc0[4 * q + 0]);
            acc0[4 * q + 1] = fmaf(a0, w.y, acc0[4 * q + 1]);
            acc0[4 * q + 2] = fmaf(a0, w.z, acc0[4 * q + 2]);
            acc0[4 * q + 3] = fmaf(a0, w.w, acc0[4 * q + 3]);
            acc1[4 * q + 0] = fmaf(a1, w.x, acc1[4 * q + 0]);
            acc1[4 * q + 1] = fmaf(a1, w.y, acc1[4 * q + 1]);
            acc1[4 * q + 2] = fmaf(a1, w.z, acc1[4 * q + 2]);
            acc1[4 * q + 3] = fmaf(a1, w.w, acc1[4 * q + 3]);
        }
    }
    __syncthreads();  // all input reads of sh + W1 reads of sW complete

    // t = ReLU(acc) overwrites sh; restage W2/b2
#pragma unroll
    for (int j = 0; j < 16; j++) {
        sh[lane * 65 + wv * 16 + j] = fmaxf(acc0[j], 0.f);
        sh[(64 + lane) * 65 + wv * 16 + j] = fmaxf(acc1[j], 0.f);
    }
    for (int i = tid; i < 4096; i += 256) sW[i] = W2[i];
    if (tid < 64) sb[tid] = b2[tid];
    __syncthreads();

    // ---- GEMM2 ----
#pragma unroll
    for (int j = 0; j < 16; j++) { acc0[j] = sb[wv * 16 + j]; acc1[j] = acc0[j]; }
    for (int k = 0; k < 64; k++) {
        float a0 = sh[lane * 65 + k];
        float a1 = sh[(64 + lane) * 65 + k];
        const float4* wr = (const float4*)(sW + k * 64 + wv * 16);
#pragma unroll
        for (int q = 0; q < 4; q++) {
            float4 w = wr[q];
            acc0[4 * q + 0] = fmaf(a0, w.x, acc0[4 * q + 0]);
            acc0[4 * q + 1] = fmaf(a0, w.y, acc0[4 * q + 1]);
            acc0[4 * q + 2] = fmaf(a0, w.z, acc0[4 * q + 2]);
            acc0[4 * q + 3] = fmaf(a0, w.w, acc0[4 * q + 3]);
            acc1[4 * q + 0] = fmaf(a1, w.x, acc1[4 * q + 0]);
            acc1[4 * q + 1] = fmaf(a1, w.y, acc1[4 * q + 1]);
            acc1[4 * q + 2] = fmaf(a1, w.z, acc1[4 * q + 2]);
            acc1[4 * q + 3] = fmaf(a1, w.w, acc1[4 * q + 3]);
        }
    }
    __syncthreads();  // all t reads complete before overwrite
#pragma unroll
    for (int j = 0; j < 16; j++) {
        sh[lane * 65 + wv * 16 + j] = acc0[j];
        sh[(64 + lane) * 65 + wv * 16 + j] = acc1[j];
    }
    __syncthreads();

    // coalesced store (float4)
#pragma unroll
    for (int i = 0; i < 8; i++) {
        int i4 = tid + 256 * i;
        int row = i4 >> 4, col = (i4 & 15) * 4;
        int grow = base + row;
        if (grow < NN) {
            const float* s = sh + row * 65 + col;
            *(float4*)(hout + (size_t)grow * HD + col) =
                make_float4(s[0], s[1], s[2], s[3]);
        }
    }

    // ---- fused BN-stats partials over the output tile ----
    {
        int col = tid & 63;
        int r0 = (tid >> 6) * 32;
        float s = 0.f, ss = 0.f;
#pragma unroll
        for (int r = 0; r < 32; r++) {
            float v = (base + r0 + r < NN) ? sh[(r0 + r) * 65 + col] : 0.f;
            s += v;
            ss += v * v;
        }
        red[0][tid >> 6][col] = s;
        red[1][tid >> 6][col] = ss;
        __syncthreads();
        if (tid < 64) {
            float S = red[0][0][col] + red[0][1][col] + red[0][2][col] + red[0][3][col];
            atomicAdd(stats + col, S);
        } else if (tid < 128) {
            float SS = red[1][0][col] + red[1][1][col] + red[1][2][col] + red[1][3][col];
            atomicAdd(stats + 64 + col, SS);
        }
    }
}

// ---------------------------------------------------------------------------
// BatchNorm (batch stats, biased var) + affine + ReLU. In-place fp32 +
// dual-write bf16 copy (gather table for the next layer's agg).
// ---------------------------------------------------------------------------
__global__ __launch_bounds__(256)
void norm_kernel(float* h, const float* __restrict__ stats,
                 const float* __restrict__ g, const float* __restrict__ be,
                 __hip_bfloat16* __restrict__ xb) {
    size_t i4 = (size_t)blockIdx.x * 256 + threadIdx.x;
    if (i4 >= (size_t)NN * HD / 4) return;
    size_t off = i4 * 4;
    int col = (int)(off & 63);
    float4 v = *(const float4*)(h + off);
    float4 sm = *(const float4*)(stats + col);
    float4 sq = *(const float4*)(stats + 64 + col);
    float4 gg = *(const float4*)(g + col);
    float4 bb = *(const float4*)(be + col);
    const float inv = 1.f / (float)NN;
    float4 o;
    {
        float mu = sm.x * inv, var = sq.x * inv - mu * mu;
        float sc = gg.x * rsqrtf(var + BN_EPS);
        o.x = fmaxf((v.x - mu) * sc + bb.x, 0.f);
    }
    {
        float mu = sm.y * inv, var = sq.y * inv - mu * mu;
        float sc = gg.y * rsqrtf(var + BN_EPS);
        o.y = fmaxf((v.y - mu) * sc + bb.y, 0.f);
    }
    {
        float mu = sm.z * inv, var = sq.z * inv - mu * mu;
        float sc = gg.z * rsqrtf(var + BN_EPS);
        o.z = fmaxf((v.z - mu) * sc + bb.z, 0.f);
    }
    {
        float mu = sm.w * inv, var = sq.w * inv - mu * mu;
        float sc = gg.w * rsqrtf(var + BN_EPS);
        o.w = fmaxf((v.w - mu) * sc + bb.w, 0.f);
    }
    *(float4*)(h + off) = o;
    union { ushort4 u; __hip_bfloat16 b[4]; } p;
    p.b[0] = __float2bfloat16(o.x);
    p.b[1] = __float2bfloat16(o.y);
    p.b[2] = __float2bfloat16(o.z);
    p.b[3] = __float2bfloat16(o.w);
    *(ushort4*)((unsigned short*)xb + off) = p.u;
}

// ---------------------------------------------------------------------------
// Mean pool: 200 partial blocks + tiny finalize.
// ---------------------------------------------------------------------------
__global__ __launch_bounds__(256)
void pool_partial_kernel(const float* __restrict__ x, const int* __restrict__ batch,
                         float* __restrict__ sums) {
    int col = threadIdx.x & 63;
    int rl = threadIdx.x >> 6;
    int rs = blockIdx.x * 250;
    int re = rs + 250;
    int cur = -1;
    float acc = 0.f;
    for (int r = rs + rl; r < re; r += 4) {
        int g = batch[r];
        float v = x[(size_t)r * HD + col];
        if (g != cur) {
            if (cur >= 0) atomicAdd(&sums[cur * HD + col], acc);
            cur = g;
            acc = v;
        } else {
            acc += v;
        }
    }
    if (cur >= 0) atomicAdd(&sums[cur * HD + col], acc);
}

__device__ __forceinline__ int lower_bound_batch(const int* __restrict__ b, int val) {
    int lo = 0, hi = NN;
    while (lo < hi) {
        int mid = (lo + hi) >> 1;
        if (b[mid] < val) lo = mid + 1;
        else hi = mid;
    }
    return lo;
}

__global__ __launch_bounds__(1024)
void pool_finalize_kernel(const float* __restrict__ sums, const int* __restrict__ batch,
                          float* __restrict__ out) {
    int g = threadIdx.x >> 6;
    int col = threadIdx.x & 63;
    int s = lower_bound_batch(batch, g);
    int e = lower_bound_batch(batch, g + 1);
    float cnt = (float)(e - s);
    out[g * HD + col] = sums[g * HD + col] / fmaxf(cnt, 1.f);
}

extern "C" void kernel_launch(void* const* d_in, const int* in_sizes, int n_in,
                              void* d_out, int out_size, void* d_ws, size_t ws_size,
                              hipStream_t stream) {
    const float* x = (const float*)d_in[0];
    const int* ei = (const int*)d_in[1];
    const int* batch = (const int*)d_in[2];
    const float* W1_0 = (const float*)d_in[3];
    const float* b1_0 = (const float*)d_in[4];
    const float* W2_0 = (const float*)d_in[5];
    const float* b2_0 = (const float*)d_in[6];
    const float* g_0 = (const float*)d_in[7];
    const float* be_0 = (const float*)d_in[8];
    const float* W1_1 = (const float*)d_in[9];
    const float* b1_1 = (const float*)d_in[10];
    const float* W2_1 = (const float*)d_in[11];
    const float* b2_1 = (const float*)d_in[12];
    const float* g_1 = (const float*)d_in[13];
    const float* be_1 = (const float*)d_in[14];

    float* out = (float*)d_out;  // node output; also x1 staging between layers

    // workspace layout (~23 MB)
    float* buf_h = (float*)d_ws;                       // 3.2M f32 (agg output)
    float* stats = buf_h + (size_t)NN * HD;            // 128 f32
    float* psums = stats + 128;                        // 1024 f32
    int* row_ptr = (int*)(psums + 1024);               // NN+1
    int* cnt = row_ptr + (NN + 2);                     // NN (also cursor)
    int* partials = cnt + NN;                          // 256
    int* poffs = partials + 256;                       // 256
    int* csr = poffs + 256;                            // NE
    __hip_bfloat16* xb = (__hip_bfloat16*)(csr + NE);  // 3.2M bf16 gather table

    dim3 b256(256);
    int egrid = (NE + 255) / 256;          // 3125
    int mlp_grid = (NN + 127) / 128;       // 391
    int norm_grid = (NN * HD / 4 + 255) / 256;
    int agg_grid = NN / 4;                 // 12500

    // ---- x->bf16 table + cnt zeroing, then CSR build ----
    x2bf_kernel<<<norm_grid, b256, 0, stream>>>(x, xb, cnt);
    count_kernel<<<egrid, b256, 0, stream>>>(ei, cnt);
    scan1_kernel<<<SCAN_BLOCKS, b256, 0, stream>>>(cnt, row_ptr, partials);
    scan2_kernel<<<1, b256, 0, stream>>>(partials, poffs);
    scan3_kernel<<<SCAN_BLOCKS, b256, 0, stream>>>(row_ptr, poffs, cnt);
    place_kernel<<<egrid, b256, 0, stream>>>(ei, cnt, csr);

    // ---- layer 0 ----
    agg_kernel<<<agg_grid, b256, 0, stream>>>(x, xb, row_ptr, csr, buf_h, stats);
    mlp_kernel<<<mlp_grid, b256, 0, stream>>>(buf_h, out, W1_0, b1_0, W2_0, b2_0, stats, psums);
    norm_kernel<<<norm_grid, b256, 0, stream>>>(out, stats, g_0, be_0, xb);

    // ---- layer 1 ----
    agg_kernel<<<agg_grid, b256, 0, stream>>>(out, xb, row_ptr, csr, buf_h, stats);
    mlp_kernel<<<mlp_grid, b256, 0, stream>>>(buf_h, out, W1_1, b1_1, W2_1, b2_1, stats, psums);
    norm_kernel<<<norm_grid, b256, 0, stream>>>(out, stats, g_1, be_1, xb);

    // ---- pool ----
    pool_partial_kernel<<<200, b256, 0, stream>>>(out, batch, psums);
    pool_finalize_kernel<<<1, dim3(1024), 0, stream>>>(psums, batch, out + (size_t)NN * HD);
}